// Round 6
// baseline (836.693 us; speedup 1.0000x reference)
//
#include <hip/hip_runtime.h>
#include <math.h>

// ---------------------------------------------------------------------------
// TTT block, first-order expansion in lambda = LR*2/(B*D) = 1.2207e-6,
// chunked linear-attention form (chunk = 64 timesteps = 1024 rows):
//   H  = tanh(alpha1*x)                  rows r = t*16+b
//   TV = H@Wsᵀ + noise ; P = H@Wpᵀ ; E0 = TV@W0ᵀ - (TV - noise)
//   Cᵀ_j = E0ᵀ_j TV_j ; S'_i = W0 - lam * Σ_{j<i} Cᵀ_j  (excl prefix, fused W0)
//   x1_i = x + P_i@S'_iᵀ-form + Kp_i@E0_i,
//     Kp_i = -lam * mask16∘(P_i TV_iᵀ)  (triangular within chunk)
//   H2 = tanh(alpha2*x1) (fused into OUT epilogue)
//   out = gelu(H2@Wp1ᵀ)*(H2@Wp2ᵀ) + x1
//
// R6: occupancy + fusion round. Evidence: R3/R4/R5 all plateau at ~65-70% CU
//   idle with 1 block/CU (128KB LDS) regardless of schedule depth -> the
//   missing ingredient is cross-block overlap (m114), which R1 had (4/CU).
//   - Geometry: BM=128, BN=256, 256 thr (4 waves, wave-tile 64x128,
//     acc[4][8]=128 AGPR), dbuf LDS = 48KB -> 2 independent blocks/CU.
//   - Schedule: T3 minimum 2-phase: STAGE(t+1,nb); ds_read(cur); MFMA;
//     fused vmcnt(0)+s_barrier. No sched_barrier pinning (m141).
//   - Fusions: TV+P one kernel (A staged once; B = [Ws;Wp] stacked panels,
//     wave wc picks output). U+V one kernel with LDS v-exchange (V never
//     materialized in HBM). 9 GEMM dispatches -> 6.
//   - T1 bijective XCD swizzle, T2 source-side granule swizzle (0 conflicts
//     measured R3-R5), T5 setprio kept.
// ---------------------------------------------------------------------------

typedef __bf16 bf16;
typedef __attribute__((ext_vector_type(8))) __bf16 bf16x8;
typedef __attribute__((ext_vector_type(4))) __bf16 bf16x4;
typedef __attribute__((ext_vector_type(4))) float f32x4;

#define LAM 1.220703125e-6f  // LR * 2 / (B*D)

enum { M_TVP = 0, M_E0 = 1, M_CT = 2, M_KP = 3, M_OUT = 4, M_UV = 5 };

struct GA {
  const bf16* A;  int lda;   // phase-1 A
  const bf16* B;  int ldb;   // phase-1 B (fused: first output's weights)
  const bf16* A2; int lda2;  // M_OUT phase-2 A (P)
  const bf16* B2; int ldb2;  // M_OUT phase-2 B (S') / fused second B (Wp,W2)
  int K;
  const float* noise;
  const float* xin;
  const float* alpha2;
  const bf16* TVb;
  bf16* H2b;
  float* outf;
  bf16* Cb;  int ldc;
  bf16* Cb2;                 // fused second output (P)
};

// async 16B global->LDS (lds dest = wave-uniform base + lane*16)
#define GLOAD_LDS16(gp, lp)                                                   \
  __builtin_amdgcn_global_load_lds(                                           \
      (const __attribute__((address_space(1))) unsigned int*)(gp),            \
      (__attribute__((address_space(3))) unsigned int*)(lp), 16, 0, 0)

// Fused drain + workgroup barrier. Single asm block: nothing schedules
// between waitcnt and s_barrier; "memory" clobber keeps LDS/global accesses
// on their own side (prevents hoisting next tile's ds_reads above it).
#define VM0_BAR()                                                             \
  asm volatile("s_waitcnt vmcnt(0)\n\ts_barrier" ::: "memory")

#define BAR() asm volatile("s_barrier" ::: "memory")

// Stage 128x32 A-tile (8KB, 2 vmem/thread). LDS linear; SOURCE k-granule
// swizzled: dest granule g of row r holds k-block g ^ ((r>>1)&3).
__device__ __forceinline__ void stage_A(const bf16* __restrict__ Ap, int ld,
                                        int k0, bf16* As, int tid) {
#pragma unroll
  for (int rr = 0; rr < 2; ++rr) {
    int c = tid + (rr << 8);                    // chunk 0..511
    int row = c >> 2;                           // 0..127
    int kb = (c & 3) ^ ((c >> 3) & 3);
    int lbase = ((tid & 192) + (rr << 8)) << 3; // wave-uniform elem base
    GLOAD_LDS16(Ap + (size_t)row * ld + k0 + (kb << 3), As + lbase);
  }
}

// Stage 256x32 B-tile (16KB, 4 vmem/thread). FUSED: rows 0..127 from B1,
// rows 128..255 from B2 (rr<2 <=> row<128, compile-time per unrolled rr).
template <bool FUSED>
__device__ __forceinline__ void stage_B(const bf16* __restrict__ B1, int ld1,
                                        const bf16* __restrict__ B2, int ld2,
                                        int k0, bf16* Bs, int tid) {
#pragma unroll
  for (int rr = 0; rr < 4; ++rr) {
    int c = tid + (rr << 8);                    // chunk 0..1023
    int row = c >> 2;                           // 0..255
    int kb = (c & 3) ^ ((c >> 3) & 3);
    int lbase = ((tid & 192) + (rr << 8)) << 3;
    const bf16* src;
    if constexpr (FUSED) {
      src = (rr < 2) ? (B1 + (size_t)row * ld1)
                     : (B2 + (size_t)(row - 128) * ld2);
    } else {
      src = B1 + (size_t)row * ld1;
    }
    GLOAD_LDS16(src + k0 + (kb << 3), Bs + lbase);
  }
}

// Stage K-tile t (A + B); M_OUT switches to phase-2 operands when t>=steps1.
template <int MODE>
__device__ __forceinline__ void stage_tile(const GA& g, int t, int steps1,
                                           const bf16* A1, const bf16* Bp1,
                                           const bf16* Bp2, const bf16* A2p,
                                           const bf16* B2p, bf16* As, bf16* Bs,
                                           int tid) {
  if constexpr (MODE == M_OUT) {
    if (t >= steps1) {
      int tt = t - steps1;
      stage_A(A2p, g.lda2, tt << 5, As, tid);
      stage_B<false>(B2p, g.ldb2, nullptr, 0, tt << 5, Bs, tid);
      return;
    }
  }
  stage_A(A1, g.lda, t << 5, As, tid);
  if constexpr (MODE == M_TVP || MODE == M_UV)
    stage_B<true>(Bp1, g.ldb, Bp2, g.ldb2, t << 5, Bs, tid);
  else
    stage_B<false>(Bp1, g.ldb, nullptr, 0, t << 5, Bs, tid);
}

// NT GEMM: C[r,c] = sum_k A[r,k]*B[c,k]; 128x256 tile, 256 threads (4 waves,
// 2x2 grid of 64x128 wave-tiles). Fused modes treat the 256 B-rows as two
// 128-row output panels. blockIdx.z batches chunks (CT/KP/OUT).
template <int MODE>
__global__ __launch_bounds__(256, 2) void gemm_nt(GA g) {
  // [dbuf][A: 128*32 then B: 256*32] = 2 x 24KB = 48KB
  __shared__ __attribute__((aligned(16))) bf16 SM[2][12288];

  // T1: bijective XCD-chunk swizzle of the flat block id (all grids %8 == 0).
  const int gx = gridDim.x, gy = gridDim.y;
  const int nwg = gx * gy * (int)gridDim.z;
  int flat = blockIdx.x + gx * (blockIdx.y + gy * blockIdx.z);
  int swz = (flat & 7) * (nwg >> 3) + (flat >> 3);
  const int bx = swz % gx;
  int t1v = swz / gx;
  const int by = t1v % gy;
  const int bz = t1v / gy;

  constexpr bool FUSED = (MODE == M_TVP || MODE == M_UV);
  const int c0 = FUSED ? (bx << 7) : (bx << 8);  // output-col base
  const int r0 = by << 7;                        // row base (chunk-rel for z)
  if constexpr (MODE == M_KP) {
    if (c0 >= r0 + 128) return;  // strictly-above-diagonal tiles never read
  }

  size_t zA = 0, zB = 0, zC = 0;
  if constexpr (MODE == M_CT) { zA = (size_t)bz << 20; zB = zA; zC = zA; }
  if constexpr (MODE == M_KP) { zA = (size_t)bz << 20; zB = zA; zC = zA; }
  if constexpr (MODE == M_OUT) { zA = (size_t)bz << 20; zB = (size_t)bz << 20; }

  const int tid = threadIdx.x;
  const int lane = tid & 63, wv = tid >> 6;
  const int wr = ((wv >> 1) & 1) << 6;  // 0 or 64
  const int wc = (wv & 1) << 7;         // 0 or 128 (B-row half)
  const int m = lane & 15, ko = lane >> 4;
  const int gsw = ko ^ ((m >> 1) & 3);  // swizzled read granule

  f32x4 acc[4][8];
#pragma unroll
  for (int i = 0; i < 4; ++i) {
#pragma unroll
    for (int j = 0; j < 8; ++j) acc[i][j] = (f32x4){0.f, 0.f, 0.f, 0.f};
  }

  int K1 = g.K;
  if constexpr (MODE == M_OUT) K1 = r0 + 128;  // triangular Kp columns
  const int steps1 = K1 >> 5;

  const bf16* A1 = g.A + zA + (size_t)r0 * g.lda;
  const bf16* Bp1 = g.B + zB + (size_t)c0 * g.ldb;
  const bf16* Bp2 = nullptr;  // fused second B
  const bf16* A2p = nullptr;  // M_OUT phase-2
  const bf16* B2p = nullptr;
  int NT = steps1;
  if constexpr (FUSED) Bp2 = g.B2 + (size_t)c0 * g.ldb2;
  if constexpr (MODE == M_OUT) {
    A2p = g.A2 + zA + (size_t)r0 * g.lda2;
    B2p = g.B2 + zA + (size_t)c0 * g.ldb2;  // S' chunk bz
    NT += 32;                                // phase-2: K=1024, BK=32
  }
  // NT: dense/fused 32; M_OUT 36..64.

  bf16* As0 = &SM[0][0];
  bf16* Bs0 = &SM[0][4096];
  bf16* As1 = &SM[1][0];
  bf16* Bs1 = &SM[1][4096];

  // -------- T3 minimum 2-phase: stage(t+1) || compute(t), 1 barrier/tile ---
  stage_tile<MODE>(g, 0, steps1, A1, Bp1, Bp2, A2p, B2p, As0, Bs0, tid);
  VM0_BAR();
  for (int t = 0; t < NT; ++t) {
    const int cur = t & 1;
    bf16* Asc = cur ? As1 : As0;
    bf16* Bsc = cur ? Bs1 : Bs0;
    if (t + 1 < NT) {
      bf16* Asn = cur ? As0 : As1;
      bf16* Bsn = cur ? Bs0 : Bs1;
      stage_tile<MODE>(g, t + 1, steps1, A1, Bp1, Bp2, A2p, B2p, Asn, Bsn, tid);
    }
    bf16x8 af[4], bfr[8];
#pragma unroll
    for (int i = 0; i < 4; ++i)
      af[i] = *(const bf16x8*)(Asc + (wr + i * 16 + m) * 32 + (gsw << 3));
#pragma unroll
    for (int j = 0; j < 8; ++j)
      bfr[j] = *(const bf16x8*)(Bsc + (wc + j * 16 + m) * 32 + (gsw << 3));
    __builtin_amdgcn_s_setprio(1);
#pragma unroll
    for (int i = 0; i < 4; ++i) {
#pragma unroll
      for (int j = 0; j < 8; ++j)
        acc[i][j] = __builtin_amdgcn_mfma_f32_16x16x32_bf16(af[i], bfr[j],
                                                            acc[i][j], 0, 0, 0);
    }
    __builtin_amdgcn_s_setprio(0);
    VM0_BAR();  // drains stage(t+1); next iter reads it safely
  }

  // ---- U+V exchange epilogue: v-half -> LDS, u-half combines ----
  if constexpr (MODE == M_UV) {
    bf16* vlds = &SM[0][0];  // 128x128 bf16 = 32KB (staging done)
    if (wc == 128) {
#pragma unroll
      for (int i = 0; i < 4; ++i) {
#pragma unroll
        for (int j = 0; j < 8; ++j) {
#pragma unroll
          for (int rg = 0; rg < 4; ++rg) {
            int row = wr + i * 16 + ko * 4 + rg;
            int col = j * 16 + m;
            int scol = col ^ (((row >> 2) & 7) << 1);  // bank spread
            vlds[row * 128 + scol] = (bf16)acc[i][j][rg];
          }
        }
      }
    }
    BAR();
    if (wc == 0) {
#pragma unroll
      for (int i = 0; i < 4; ++i) {
#pragma unroll
        for (int j = 0; j < 8; ++j) {
#pragma unroll
          for (int rg = 0; rg < 4; ++rg) {
            int row = wr + i * 16 + ko * 4 + rg;
            int col = j * 16 + m;
            int scol = col ^ (((row >> 2) & 7) << 1);
            float vv = (float)vlds[row * 128 + scol];
            float u = acc[i][j][rg];
            float gl = 0.5f * u * (1.0f + erff(u * 0.70710678118654752f));
            size_t oi = (size_t)(r0 + row) * 1024 + (c0 + col);
            g.outf[oi] = gl * vv + g.outf[oi];
          }
        }
      }
    }
    return;
  }

  // C/D layout (m89/m91-verified): col = lane&15, row = (lane>>4)*4 + reg
#pragma unroll
  for (int i = 0; i < 4; ++i) {
#pragma unroll
    for (int j = 0; j < 8; ++j) {
      const int colw = j * 16 + m;  // col within panel (fused) / half (plain)
      const int gc = FUSED ? (c0 + colw) : (c0 + wc + colw);
#pragma unroll
      for (int rg = 0; rg < 4; ++rg) {
        const int grl = r0 + wr + i * 16 + ko * 4 + rg;
        float v = acc[i][j][rg];
        if constexpr (MODE == M_TVP) {
          if (wc == 0) {  // TV = acc + noise
            int t = grl >> 4, b = grl & 15;
            float tv = v + g.noise[((size_t)b << 20) + ((size_t)t << 10) + gc];
            g.Cb[(size_t)grl * g.ldc + gc] = (bf16)tv;
          } else {        // P
            g.Cb2[(size_t)grl * 1024 + gc] = (bf16)v;
          }
        } else if constexpr (MODE == M_E0) {
          int t = grl >> 4, b = grl & 15;
          size_t ni = ((size_t)b << 20) + ((size_t)t << 10) + gc;
          float tvv = (float)g.TVb[(size_t)grl * 1024 + gc];
          float e0 = v - (tvv - g.noise[ni]);  // state = tv - noise
          g.Cb[(size_t)grl * g.ldc + gc] = (bf16)e0;
        } else if constexpr (MODE == M_CT) {
          g.Cb[zC + (size_t)grl * g.ldc + gc] = (bf16)v;
        } else if constexpr (MODE == M_KP) {
          float sv = ((gc >> 4) <= (grl >> 4)) ? (-LAM * v) : 0.0f;
          g.Cb[zC + (size_t)grl * g.ldc + gc] = (bf16)sv;
        } else if constexpr (MODE == M_OUT) {
          int rgl = (bz << 10) + grl;
          int t = rgl >> 4, b = rgl & 15;
          size_t oi = ((size_t)b << 20) + ((size_t)t << 10) + gc;
          float x1 = v + g.xin[oi];
          g.outf[oi] = x1;
          g.H2b[oi] = (bf16)tanhf(g.alpha2[gc] * x1);  // fused norm_2
        }
      }
    }
  }
}

// fp32 -> bf16 of the 5 weight matrices (concatenated dst)
__global__ void ew_convert(const float* w0, const float* w1, const float* w2,
                           const float* w3, const float* w4, bf16* dst) {
  int gid = blockIdx.x * 256 + threadIdx.x;
  int i4 = gid << 2;
  int mm = i4 >> 20;
  const float* src = (mm == 0) ? w0 : (mm == 1) ? w1 : (mm == 2) ? w2
                     : (mm == 3) ? w3 : w4;
  int off = i4 & 1048575;
  float4 v = *(const float4*)(src + off);
  bf16x4 o;
  o[0] = (bf16)v.x; o[1] = (bf16)v.y; o[2] = (bf16)v.z; o[3] = (bf16)v.w;
  *(bf16x4*)(dst + i4) = o;
}

// H[(t*16+b), d] = bf16(tanh(alpha1[d] * x[b,t,d]))
__global__ void ew_h1(const float* __restrict__ x, const float* __restrict__ a1,
                      bf16* __restrict__ H) {
  int gid = blockIdx.x * 256 + threadIdx.x;
  int i4 = gid << 2;
  int d = i4 & 1023;
  int t = (i4 >> 10) & 1023;
  int b = i4 >> 20;
  float4 xv = *(const float4*)(x + i4);
  float4 av = *(const float4*)(a1 + d);
  bf16x4 o;
  o[0] = (bf16)tanhf(av.x * xv.x);
  o[1] = (bf16)tanhf(av.y * xv.y);
  o[2] = (bf16)tanhf(av.z * xv.z);
  o[3] = (bf16)tanhf(av.w * xv.w);
  *(bf16x4*)(H + (((size_t)((t << 4) + b)) << 10) + d) = o;
}

// S'[j] = W0 - lam * (exclusive prefix of C over chunks); in-place safe
__global__ void prefix_s(const bf16* __restrict__ C, bf16* __restrict__ S,
                         const bf16* __restrict__ W0) {
  int gid = blockIdx.x * 256 + threadIdx.x;  // 262144 threads
  size_t base = (size_t)gid << 2;
  bf16x4 wv = *(const bf16x4*)(W0 + base);
  float w0 = (float)wv[0], w1 = (float)wv[1], w2 = (float)wv[2],
        w3 = (float)wv[3];
  float ac0 = 0.f, ac1 = 0.f, ac2 = 0.f, ac3 = 0.f;
#pragma unroll
  for (int j = 0; j < 16; ++j) {
    size_t off = ((size_t)j << 20) + base;
    bf16x4 c = *(const bf16x4*)(C + off);
    bf16x4 o;
    o[0] = (bf16)(w0 - LAM * ac0);
    o[1] = (bf16)(w1 - LAM * ac1);
    o[2] = (bf16)(w2 - LAM * ac2);
    o[3] = (bf16)(w3 - LAM * ac3);
    *(bf16x4*)(S + off) = o;
    ac0 += (float)c[0]; ac1 += (float)c[1];
    ac2 += (float)c[2]; ac3 += (float)c[3];
  }
}

// [16384 x 1024] -> chunk-blocked [16][1024][1024] bf16 transpose.
// out[chunk][d][n'] = in[chunk*1024 + n'][d]; 64x64 LDS tiles.
__global__ __launch_bounds__(256) void tr_e0(const bf16* __restrict__ in,
                                             bf16* __restrict__ out) {
  __shared__ bf16 tile[64][72];
  int c0 = blockIdx.x << 6;   // d-block
  int r0 = blockIdx.y << 6;   // n-block (64-aligned; never straddles chunks)
  int tid = threadIdx.x;
  int lr = tid >> 4;
  int lc = (tid & 15) << 2;
#pragma unroll
  for (int ph = 0; ph < 4; ++ph) {
    int row = lr + (ph << 4);
    bf16x4 v = *(const bf16x4*)(in + (size_t)(r0 + row) * 1024 + c0 + lc);
    *(bf16x4*)(&tile[row][lc]) = v;
  }
  __syncthreads();
  const size_t cbase = ((size_t)(r0 >> 10) << 20) + (r0 & 1023) + lc;
#pragma unroll
  for (int ph = 0; ph < 4; ++ph) {
    int oc = lr + (ph << 4);
    bf16x4 v;
    v[0] = tile[lc + 0][oc];
    v[1] = tile[lc + 1][oc];
    v[2] = tile[lc + 2][oc];
    v[3] = tile[lc + 3][oc];
    *(bf16x4*)(out + cbase + (size_t)(c0 + oc) * 1024) = v;
  }
}

extern "C" void kernel_launch(void* const* d_in, const int* in_sizes, int n_in,
                              void* d_out, int out_size, void* d_ws,
                              size_t ws_size, hipStream_t stream) {
  (void)in_sizes; (void)n_in; (void)out_size;
  const float* x = (const float*)d_in[0];
  const float* noise = (const float*)d_in[1];
  const float* a1 = (const float*)d_in[2];
  const float* a2 = (const float*)d_in[3];
  const float* Wmap = (const float*)d_in[4];
  const float* Wst = (const float*)d_in[5];
  const float* Wpr = (const float*)d_in[6];
  const float* Wp1 = (const float*)d_in[7];
  const float* Wp2 = (const float*)d_in[8];
  float* out = (float*)d_out;

  const size_t MB32 = (size_t)16384 * 1024 * 2;  // 32 MiB
  const size_t NEED = 5 * MB32 + 5 * (size_t)1048576 * 2;  // 170 MiB
  if (ws_size < NEED) return;  // insufficient scratch; fail loudly

  char* ws = (char*)d_ws;
  bf16* s0 = (bf16*)(ws);              // H -> E0 -> C^T -> S'
  bf16* s1 = (bf16*)(ws + MB32);       // TV -> H2
  bf16* s2 = (bf16*)(ws + 2 * MB32);   // P
  bf16* s3 = (bf16*)(ws + 3 * MB32);   // E0^T chunk-blocked [16][1024][1024]
  bf16* s4 = (bf16*)(ws + 4 * MB32);   // TV^T chunk-blocked -> Kp
  bf16* Wcat = (bf16*)(ws + 5 * MB32);
  bf16* Wb0 = Wcat;
  bf16* Wsb = Wcat + (1 << 20);
  bf16* Wpb = Wcat + 2 * (1 << 20);
  bf16* W1b = Wcat + 3 * (1 << 20);
  bf16* W2b = Wcat + 4 * (1 << 20);

  ew_convert<<<5120, 256, 0, stream>>>(Wmap, Wst, Wpr, Wp1, Wp2, Wcat);
  ew_h1<<<16384, 256, 0, stream>>>(x, a1, s0);

  {  // TV = H@Wsᵀ + noise -> s1 ; P = H@Wpᵀ -> s2   (fused, A staged once)
    GA g{};
    g.A = s0; g.lda = 1024;
    g.B = Wsb; g.ldb = 1024; g.B2 = Wpb; g.ldb2 = 1024;
    g.K = 1024; g.noise = noise;
    g.Cb = s1; g.ldc = 1024; g.Cb2 = s2;
    gemm_nt<M_TVP><<<dim3(8, 128), 256, 0, stream>>>(g);
  }
  {  // E0 = TV@W0ᵀ - (TV - noise) -> s0 (H dead)
    GA g{};
    g.A = s1; g.lda = 1024; g.B = Wb0; g.ldb = 1024; g.K = 1024;
    g.noise = noise; g.TVb = s1; g.Cb = s0; g.ldc = 1024;
    gemm_nt<M_E0><<<dim3(4, 128), 256, 0, stream>>>(g);
  }
  tr_e0<<<dim3(16, 256), 256, 0, stream>>>(s0, s3);  // E0^T (chunk-blocked)
  tr_e0<<<dim3(16, 256), 256, 0, stream>>>(s1, s4);  // TV^T (chunk-blocked)

  {  // C^T_j[r,c] = sum_n' E0^T_j[r,n']*TV^T_j[c,n'] -> s0[j]
    GA g{};
    g.A = s3; g.lda = 1024; g.B = s4; g.ldb = 1024; g.K = 1024;
    g.Cb = s0; g.ldc = 1024;
    gemm_nt<M_CT><<<dim3(4, 8, 16), 256, 0, stream>>>(g);
  }
  prefix_s<<<1024, 256, 0, stream>>>(s0, s0, Wb0);  // S' = W0 - lam*prefix

  {  // Kp_i = -lam * mask16 ∘ (P_i @ TV_iᵀ) -> s4 (TV^T dead)
    GA g{};
    g.A = s2; g.lda = 1024; g.B = s1; g.ldb = 1024; g.K = 1024;
    g.Cb = s4; g.ldc = 1024;
    gemm_nt<M_KP><<<dim3(4, 8, 16), 256, 0, stream>>>(g);
  }
  {  // x1_i = Kp_i@E0_i (tri-K) + P_i@S'_i + x -> d_out ; H2 -> s1
    GA g{};
    g.A = s4; g.lda = 1024;        // Kp chunk
    g.B = s3; g.ldb = 1024;        // E0^T chunk-blocked
    g.A2 = s2; g.lda2 = 1024;      // P chunk
    g.B2 = s0; g.ldb2 = 1024;      // S' chunk
    g.xin = x; g.outf = out;
    g.alpha2 = a2; g.H2b = s1;     // fused tanh(alpha2*x1) (TV dead)
    gemm_nt<M_OUT><<<dim3(4, 8, 16), 256, 0, stream>>>(g);
  }
  {  // out = gelu(H2@Wp1ᵀ) * (H2@Wp2ᵀ) + x1   (fused; V stays in LDS)
    GA g{};
    g.A = s1; g.lda = 1024;
    g.B = W1b; g.ldb = 1024; g.B2 = W2b; g.ldb2 = 1024;
    g.K = 1024; g.outf = out;
    gemm_nt<M_UV><<<dim3(8, 128), 256, 0, stream>>>(g);
  }
}

// Round 7
// 831.046 us; speedup vs baseline: 1.0068x; 1.0068x over previous
//
#include <hip/hip_runtime.h>
#include <math.h>

// ---------------------------------------------------------------------------
// TTT block, first-order expansion in lambda = LR*2/(B*D) = 1.2207e-6,
// chunked linear-attention form (chunk = 64 timesteps = 1024 rows):
//   H  = tanh(alpha1*x)                  rows r = t*16+b
//   TV = H@Wsᵀ + noise ; P = H@Wpᵀ ; E0 = TV@W0ᵀ - (TV - noise)
//   Cᵀ_j = E0ᵀ_j TV_j ; S'_i = W0 - lam * Σ_{j<i} Cᵀ_j  (excl prefix, fused W0)
//   x1_i = x + P_i@S'_iᵀ-form + Kp_i@E0_i,
//     Kp_i = -lam * mask16∘(P_i TV_iᵀ)  (triangular within chunk)
//   H2 = tanh(alpha2*x1) (fused into OUT epilogue)
//   out = gelu(H2@Wp1ᵀ)*(H2@Wp2ᵀ) + x1
//
// R7 = R4 (best measured: ring-4 / depth-2 / counted vmcnt, 256x256, 8 waves)
//   + consolidation:
//   - M_TVP: TV and P in ONE dispatch. Wsb/Wpb are adjacent in Wcat, so
//     B is simply a 2048-row matrix; gx=8; epilogue routes gc<1024 -> TV
//     (+noise) else -> P. Identical staging math to R4.
//   - M_UV: U=H2@W1^T and V=H2@W2^T in ONE dispatch; B-tile rows 0..127
//     from W1-panel, 128..255 from W2-panel (compile-time split per rr);
//     waves wc<128 own U, wc>=128 own V; post-loop LDS exchange (pad-136
//     stride) -> V never touches HBM (saves 64MB traffic + 1 dispatch).
//   - chunk-blocked transposes [16][1024][1024] (R5-verified): CT/OUT
//     stage E0^T/TV^T at 2KB stride.
//   Loop/schedule/swizzles byte-identical to R4 (0 bank conflicts measured).
// ---------------------------------------------------------------------------

typedef __bf16 bf16;
typedef __attribute__((ext_vector_type(8))) __bf16 bf16x8;
typedef __attribute__((ext_vector_type(4))) __bf16 bf16x4;
typedef __attribute__((ext_vector_type(4))) float f32x4;

#define LAM 1.220703125e-6f  // LR * 2 / (B*D)

enum { M_TVP = 0, M_E0 = 1, M_CT = 2, M_KP = 3, M_OUT = 4, M_UV = 5 };

struct GA {
  const bf16* A;  int lda;   // phase-1 operands
  const bf16* B;  int ldb;
  const bf16* Bb;            // M_UV second B panel (W2)
  const bf16* A2; int lda2;  // M_OUT phase-2 A (P)
  const bf16* B2; int ldb2;  // M_OUT phase-2 B (S')
  int K;
  const float* noise;
  const float* xin;
  const float* alpha2;
  const bf16* TVb;
  bf16* H2b;
  float* outf;
  bf16* Cb;  int ldc;
  bf16* Cb2;                 // M_TVP second output (P)
};

// async 16B global->LDS (lds dest = wave-uniform base + lane*16)
#define GLOAD_LDS16(gp, lp)                                                   \
  __builtin_amdgcn_global_load_lds(                                           \
      (const __attribute__((address_space(1))) unsigned int*)(gp),            \
      (__attribute__((address_space(3))) unsigned int*)(lp), 16, 0, 0)

// Fused counted-wait + workgroup barrier (single asm block: nothing schedules
// between them; "memory" clobber orders all LDS/global ops; sched_barrier
// pins the machine scheduler — rule #18).
#define WAIT_BARRIER(N)                                                       \
  do {                                                                        \
    asm volatile("s_waitcnt vmcnt(" #N ")\n\ts_barrier" ::: "memory");        \
    __builtin_amdgcn_sched_barrier(0);                                        \
  } while (0)

#define BAR()                                                                 \
  do {                                                                        \
    asm volatile("s_barrier" ::: "memory");                                   \
    __builtin_amdgcn_sched_barrier(0);                                        \
  } while (0)

// Stage one 256x32 matrix tile (16KB, 2 vmem/thread) into a linear LDS slot.
// SOURCE k-granule swizzled: dest granule g of row r holds k-block
// g ^ ((r>>1)&3)  (read side uses gsw = ko ^ ((m>>1)&3); verified 0 bank
// conflicts in R3-R6).
__device__ __forceinline__ void stage_mat(const bf16* __restrict__ Sp, int ld,
                                          int k0, bf16* Ls, int tid) {
#pragma unroll
  for (int rr = 0; rr < 2; ++rr) {
    int c = tid + (rr << 9);                    // chunk 0..1023 (16B each)
    int row = c >> 2;                           // 0..255
    int kb = (c & 3) ^ ((c >> 3) & 3);
    int lbase = ((tid & 448) + (rr << 9)) << 3; // wave-uniform LDS elem base
    GLOAD_LDS16(Sp + (size_t)row * ld + k0 + (kb << 3), Ls + lbase);
  }
}

// M_UV B-tile: rows 0..127 = W1 panel, rows 128..255 = W2 panel (same cols).
// Split is compile-time per rr (rr==0 <=> row<128). ld fixed 1024.
__device__ __forceinline__ void stage_uvB(const bf16* __restrict__ W1p,
                                          const bf16* __restrict__ W2p,
                                          int k0, bf16* Ls, int tid) {
  {
    int c = tid;                                // rows 0..127
    int row = c >> 2;
    int kb = (c & 3) ^ ((c >> 3) & 3);
    int lbase = (tid & 448) << 3;
    GLOAD_LDS16(W1p + (size_t)row * 1024 + k0 + (kb << 3), Ls + lbase);
  }
  {
    int c = tid + 512;                          // rows 128..255 -> W2 0..127
    int row = (c >> 2) - 128;
    int kb = (c & 3) ^ ((c >> 3) & 3);
    int lbase = ((tid & 448) + 512) << 3;
    GLOAD_LDS16(W2p + (size_t)row * 1024 + k0 + (kb << 3), Ls + lbase);
  }
}

// Stage K-tile s into (As,Bs): 4 vmem/thread total (ledger: 8/4/0 constants).
template <int MODE>
__device__ __forceinline__ void stage_sel(const GA& g, int s, int steps1,
                                          const bf16* A1, const bf16* B1,
                                          const bf16* B1b, const bf16* A2,
                                          const bf16* B2, bf16* As, bf16* Bs,
                                          int tid) {
  if constexpr (MODE == M_OUT) {
    if (s >= steps1) {
      int k0 = (s - steps1) << 5;
      stage_mat(A2, g.lda2, k0, As, tid);
      stage_mat(B2, g.ldb2, k0, Bs, tid);
      return;
    }
  }
  int k0 = s << 5;
  stage_mat(A1, g.lda, k0, As, tid);
  if constexpr (MODE == M_UV)
    stage_uvB(B1, B1b, k0, Bs, tid);
  else
    stage_mat(B1, g.ldb, k0, Bs, tid);
}

// 32 MFMAs on one staged tile pair; wave-tile 128x64.
__device__ __forceinline__ void compute_step(const bf16* As, const bf16* Bs,
                                             int wr, int wc, int m, int gsw,
                                             f32x4 acc[8][4]) {
  bf16x8 af[8], bfr[4];
#pragma unroll
  for (int i = 0; i < 8; ++i)
    af[i] = *(const bf16x8*)(As + (wr + i * 16 + m) * 32 + (gsw << 3));
#pragma unroll
  for (int j = 0; j < 4; ++j)
    bfr[j] = *(const bf16x8*)(Bs + (wc + j * 16 + m) * 32 + (gsw << 3));
  __builtin_amdgcn_s_setprio(1);
#pragma unroll
  for (int i = 0; i < 8; ++i) {
#pragma unroll
    for (int j = 0; j < 4; ++j)
      acc[i][j] =
          __builtin_amdgcn_mfma_f32_16x16x32_bf16(af[i], bfr[j], acc[i][j], 0, 0, 0);
  }
  __builtin_amdgcn_s_setprio(0);
}

// NT GEMM: C[r,c] = sum_k A[r,k]*B[c,k]; 256x256 tile, 512 threads (8 waves,
// 2x4 grid of 128x64 wave-tiles). blockIdx.z batches chunks (CT/KP/OUT).
template <int MODE>
__global__ __launch_bounds__(512, 2) void gemm_nt(GA g) {
  __shared__ __attribute__((aligned(16))) bf16 As[4][256 * 32];
  __shared__ __attribute__((aligned(16))) bf16 Bs[4][256 * 32];

  // T1: bijective XCD-chunk swizzle of the flat block id (all grids %8 == 0).
  const int gx = gridDim.x, gy = gridDim.y;
  const int nwg = gx * gy * (int)gridDim.z;
  int flat = blockIdx.x + gx * (blockIdx.y + gy * blockIdx.z);
  int swz = (flat & 7) * (nwg >> 3) + (flat >> 3);
  const int bx = swz % gx;
  int t1v = swz / gx;
  const int by = t1v % gy;
  const int bz = t1v / gy;

  // M_UV: 128-col output panels (U and V of the same cols share the block).
  const int c0 = (MODE == M_UV) ? (bx << 7) : (bx << 8);
  const int r0 = by << 8;
  if constexpr (MODE == M_KP) {
    if (c0 > r0) return;  // strictly-above-diagonal tiles never read
  }

  size_t zA = 0, zB = 0, zC = 0;
  if constexpr (MODE == M_CT) { zA = (size_t)bz << 20; zB = zA; zC = zA; }
  if constexpr (MODE == M_KP) { zA = (size_t)bz << 20; zB = zA; zC = zA; }
  if constexpr (MODE == M_OUT) { zA = (size_t)bz << 20; zB = (size_t)bz << 20; }

  const int tid = threadIdx.x;
  const int lane = tid & 63, wv = tid >> 6;
  const int wr = (wv >> 2) << 7;   // 0 or 128
  const int wc = (wv & 3) << 6;    // 0,64,128,192
  const int m = lane & 15, ko = lane >> 4;
  const int gsw = ko ^ ((m >> 1) & 3);  // swizzled read granule

  f32x4 acc[8][4];
#pragma unroll
  for (int i = 0; i < 8; ++i) {
#pragma unroll
    for (int j = 0; j < 4; ++j) acc[i][j] = (f32x4){0.f, 0.f, 0.f, 0.f};
  }

  int K1 = g.K;
  if constexpr (MODE == M_OUT) K1 = r0 + 256;  // triangular Kp columns
  const int steps1 = K1 >> 5;

  const bf16* A1 = g.A + zA + (size_t)r0 * g.lda;
  const bf16* B1 = g.B + zB + (size_t)c0 * g.ldb;
  const bf16* B1b = nullptr;
  const bf16* A2 = nullptr;
  const bf16* B2 = nullptr;
  int total = steps1;
  if constexpr (MODE == M_UV) B1b = g.Bb + (size_t)c0 * 1024;
  if constexpr (MODE == M_OUT) {
    A2 = g.A2 + zA + (size_t)r0 * g.lda2;
    B2 = g.B2 + zA + (size_t)c0 * g.ldb2;  // S' chunk bz
    total += 32;                            // phase-2: K=1024, BK=32
  }
  // total: dense 32; M_OUT 36..64 — always even, >= 4.

  // -------- ring-4 pipeline, prefetch distance 2, counted vmcnt --------
  // Race proof: stage(s+2) overwrites slot[(s-2)&3], last read by
  // compute(s-2); every wave passed barrier(s-1) only after compute(s-2)'s
  // ds_reads completed everywhere, and stage(s+2) issues after barrier(s-1).
  stage_sel<MODE>(g, 0, steps1, A1, B1, B1b, A2, B2, As[0], Bs[0], tid);
  stage_sel<MODE>(g, 1, steps1, A1, B1, B1b, A2, B2, As[1], Bs[1], tid);

  int s = 0;
  for (; s < total - 2; ++s) {
    const int rn = (s + 2) & 3;
    stage_sel<MODE>(g, s + 2, steps1, A1, B1, B1b, A2, B2, As[rn], Bs[rn], tid);
    WAIT_BARRIER(8);  // stage(s) landed; s+1,s+2 (8 vmem) stay in flight
    compute_step(As[s & 3], Bs[s & 3], wr, wc, m, gsw, acc);
  }
  WAIT_BARRIER(4);
  compute_step(As[s & 3], Bs[s & 3], wr, wc, m, gsw, acc);
  ++s;
  WAIT_BARRIER(0);
  compute_step(As[s & 3], Bs[s & 3], wr, wc, m, gsw, acc);

  // ---- M_UV: V waves hand their tile to U waves through LDS; V never
  // touches HBM. vlds overlays the (retired) staging buffers, pad-136 cols.
  if constexpr (MODE == M_UV) {
    bf16* vlds = &As[0][0];  // 256*136*2B = 69.6KB <= 128KB available
    BAR();                   // all compute_step LDS reads done before overlay
    if (wc >= 128) {
#pragma unroll
      for (int i = 0; i < 8; ++i) {
#pragma unroll
        for (int j = 0; j < 4; ++j) {
          const int cl = (wc - 128) + j * 16 + m;
#pragma unroll
          for (int rg = 0; rg < 4; ++rg) {
            const int rl = wr + i * 16 + ko * 4 + rg;
            vlds[rl * 136 + cl] = (bf16)acc[i][j][rg];
          }
        }
      }
    }
    BAR();
    if (wc < 128) {
#pragma unroll
      for (int i = 0; i < 8; ++i) {
#pragma unroll
        for (int j = 0; j < 4; ++j) {
          const int cl = wc + j * 16 + m;
#pragma unroll
          for (int rg = 0; rg < 4; ++rg) {
            const int rl = wr + i * 16 + ko * 4 + rg;
            float u = acc[i][j][rg];
            float vv = (float)vlds[rl * 136 + cl];
            float gl = 0.5f * u * (1.0f + erff(u * 0.70710678118654752f));
            size_t oi = (size_t)(r0 + rl) * 1024 + (c0 + cl);
            g.outf[oi] = gl * vv + g.outf[oi];
          }
        }
      }
    }
    return;
  }

  // C/D layout (m89/m91-verified): col = lane&15, row = (lane>>4)*4 + reg
#pragma unroll
  for (int i = 0; i < 8; ++i) {
#pragma unroll
    for (int j = 0; j < 4; ++j) {
      const int gc = c0 + wc + j * 16 + m;
#pragma unroll
      for (int rg = 0; rg < 4; ++rg) {
        const int grl = r0 + wr + i * 16 + ko * 4 + rg;
        float v = acc[i][j][rg];
        if constexpr (MODE == M_TVP) {
          if (gc < 1024) {  // TV panel (+noise)
            int t = grl >> 4, b = grl & 15;
            float tv = v + g.noise[((size_t)b << 20) + ((size_t)t << 10) + gc];
            g.Cb[(size_t)grl * g.ldc + gc] = (bf16)tv;
          } else {          // P panel
            g.Cb2[(size_t)grl * 1024 + (gc - 1024)] = (bf16)v;
          }
        } else if constexpr (MODE == M_E0) {
          int t = grl >> 4, b = grl & 15;
          size_t ni = ((size_t)b << 20) + ((size_t)t << 10) + gc;
          float tvv = (float)g.TVb[(size_t)grl * 1024 + gc];
          float e0 = v - (tvv - g.noise[ni]);  // state = tv - noise
          g.Cb[(size_t)grl * g.ldc + gc] = (bf16)e0;
        } else if constexpr (MODE == M_CT) {
          g.Cb[zC + (size_t)grl * g.ldc + gc] = (bf16)v;
        } else if constexpr (MODE == M_KP) {
          float sv = ((gc >> 4) <= (grl >> 4)) ? (-LAM * v) : 0.0f;
          g.Cb[zC + (size_t)grl * g.ldc + gc] = (bf16)sv;
        } else if constexpr (MODE == M_OUT) {
          int rgl = (bz << 10) + grl;
          int t = rgl >> 4, b = rgl & 15;
          size_t oi = ((size_t)b << 20) + ((size_t)t << 10) + gc;
          float x1 = v + g.xin[oi];
          g.outf[oi] = x1;
          g.H2b[oi] = (bf16)tanhf(g.alpha2[gc] * x1);  // fused norm_2
        }
      }
    }
  }
}

// fp32 -> bf16 of the 5 weight matrices (concatenated dst)
__global__ void ew_convert(const float* w0, const float* w1, const float* w2,
                           const float* w3, const float* w4, bf16* dst) {
  int gid = blockIdx.x * 256 + threadIdx.x;
  int i4 = gid << 2;
  int mm = i4 >> 20;
  const float* src = (mm == 0) ? w0 : (mm == 1) ? w1 : (mm == 2) ? w2
                     : (mm == 3) ? w3 : w4;
  int off = i4 & 1048575;
  float4 v = *(const float4*)(src + off);
  bf16x4 o;
  o[0] = (bf16)v.x; o[1] = (bf16)v.y; o[2] = (bf16)v.z; o[3] = (bf16)v.w;
  *(bf16x4*)(dst + i4) = o;
}

// H[(t*16+b), d] = bf16(tanh(alpha1[d] * x[b,t,d]))
__global__ void ew_h1(const float* __restrict__ x, const float* __restrict__ a1,
                      bf16* __restrict__ H) {
  int gid = blockIdx.x * 256 + threadIdx.x;
  int i4 = gid << 2;
  int d = i4 & 1023;
  int t = (i4 >> 10) & 1023;
  int b = i4 >> 20;
  float4 xv = *(const float4*)(x + i4);
  float4 av = *(const float4*)(a1 + d);
  bf16x4 o;
  o[0] = (bf16)tanhf(av.x * xv.x);
  o[1] = (bf16)tanhf(av.y * xv.y);
  o[2] = (bf16)tanhf(av.z * xv.z);
  o[3] = (bf16)tanhf(av.w * xv.w);
  *(bf16x4*)(H + (((size_t)((t << 4) + b)) << 10) + d) = o;
}

// S'[j] = W0 - lam * (exclusive prefix of C over chunks); in-place safe
__global__ void prefix_s(const bf16* __restrict__ C, bf16* __restrict__ S,
                         const bf16* __restrict__ W0) {
  int gid = blockIdx.x * 256 + threadIdx.x;  // 262144 threads
  size_t base = (size_t)gid << 2;
  bf16x4 wv = *(const bf16x4*)(W0 + base);
  float w0 = (float)wv[0], w1 = (float)wv[1], w2 = (float)wv[2],
        w3 = (float)wv[3];
  float ac0 = 0.f, ac1 = 0.f, ac2 = 0.f, ac3 = 0.f;
#pragma unroll
  for (int j = 0; j < 16; ++j) {
    size_t off = ((size_t)j << 20) + base;
    bf16x4 c = *(const bf16x4*)(C + off);
    bf16x4 o;
    o[0] = (bf16)(w0 - LAM * ac0);
    o[1] = (bf16)(w1 - LAM * ac1);
    o[2] = (bf16)(w2 - LAM * ac2);
    o[3] = (bf16)(w3 - LAM * ac3);
    *(bf16x4*)(S + off) = o;
    ac0 += (float)c[0]; ac1 += (float)c[1];
    ac2 += (float)c[2]; ac3 += (float)c[3];
  }
}

// [16384 x 1024] -> chunk-blocked [16][1024][1024] bf16 transpose.
// out[chunk][d][n'] = in[chunk*1024 + n'][d]; 64x64 LDS tiles.
__global__ __launch_bounds__(256) void tr_e0(const bf16* __restrict__ in,
                                             bf16* __restrict__ out) {
  __shared__ bf16 tile[64][72];
  int c0 = blockIdx.x << 6;   // d-block
  int r0 = blockIdx.y << 6;   // n-block (64-aligned; never straddles chunks)
  int tid = threadIdx.x;
  int lr = tid >> 4;
  int lc = (tid & 15) << 2;
#pragma unroll
  for (int ph = 0; ph < 4; ++ph) {
    int row = lr + (ph << 4);
    bf16x4 v = *(const bf16x4*)(in + (size_t)(r0 + row) * 1024 + c0 + lc);
    *(bf16x4*)(&tile[row][lc]) = v;
  }
  __syncthreads();
  const size_t cbase = ((size_t)(r0 >> 10) << 20) + (r0 & 1023) + lc;
#pragma unroll
  for (int ph = 0; ph < 4; ++ph) {
    int oc = lr + (ph << 4);
    bf16x4 v;
    v[0] = tile[lc + 0][oc];
    v[1] = tile[lc + 1][oc];
    v[2] = tile[lc + 2][oc];
    v[3] = tile[lc + 3][oc];
    *(bf16x4*)(out + cbase + (size_t)(c0 + oc) * 1024) = v;
  }
}

extern "C" void kernel_launch(void* const* d_in, const int* in_sizes, int n_in,
                              void* d_out, int out_size, void* d_ws,
                              size_t ws_size, hipStream_t stream) {
  (void)in_sizes; (void)n_in; (void)out_size;
  const float* x = (const float*)d_in[0];
  const float* noise = (const float*)d_in[1];
  const float* a1 = (const float*)d_in[2];
  const float* a2 = (const float*)d_in[3];
  const float* Wmap = (const float*)d_in[4];
  const float* Wst = (const float*)d_in[5];
  const float* Wpr = (const float*)d_in[6];
  const float* Wp1 = (const float*)d_in[7];
  const float* Wp2 = (const float*)d_in[8];
  float* out = (float*)d_out;

  const size_t MB32 = (size_t)16384 * 1024 * 2;  // 32 MiB
  const size_t NEED = 5 * MB32 + 5 * (size_t)1048576 * 2;  // 170 MiB
  if (ws_size < NEED) return;  // insufficient scratch; fail loudly

  char* ws = (char*)d_ws;
  bf16* s0 = (bf16*)(ws);              // H -> E0 -> C^T -> S'
  bf16* s1 = (bf16*)(ws + MB32);       // TV -> H2
  bf16* s2 = (bf16*)(ws + 2 * MB32);   // P
  bf16* s3 = (bf16*)(ws + 3 * MB32);   // E0^T chunk-blocked [16][1024][1024]
  bf16* s4 = (bf16*)(ws + 4 * MB32);   // TV^T chunk-blocked -> Kp
  bf16* Wcat = (bf16*)(ws + 5 * MB32);
  bf16* Wb0 = Wcat;
  bf16* Wsb = Wcat + (1 << 20);        // adjacent: Wsb then Wpb (TVP fusion)
  bf16* W1b = Wcat + 3 * (1 << 20);    // adjacent: W1b then W2b
  bf16* W2b = Wcat + 4 * (1 << 20);

  ew_convert<<<5120, 256, 0, stream>>>(Wmap, Wst, Wpr, Wp1, Wp2, Wcat);
  ew_h1<<<16384, 256, 0, stream>>>(x, a1, s0);

  {  // TV = H@Wsᵀ + noise -> s1 ; P = H@Wpᵀ -> s2  (one dispatch, B=2048 rows)
    GA g{};
    g.A = s0; g.lda = 1024; g.B = Wsb; g.ldb = 1024; g.K = 1024;
    g.noise = noise; g.Cb = s1; g.ldc = 1024; g.Cb2 = s2;
    gemm_nt<M_TVP><<<dim3(8, 64), 512, 0, stream>>>(g);
  }
  {  // E0 = TV@W0ᵀ - (TV - noise) -> s0 (H dead)
    GA g{};
    g.A = s1; g.lda = 1024; g.B = Wb0; g.ldb = 1024; g.K = 1024;
    g.noise = noise; g.TVb = s1; g.Cb = s0; g.ldc = 1024;
    gemm_nt<M_E0><<<dim3(4, 64), 512, 0, stream>>>(g);
  }
  tr_e0<<<dim3(16, 256), 256, 0, stream>>>(s0, s3);  // E0^T (chunk-blocked)
  tr_e0<<<dim3(16, 256), 256, 0, stream>>>(s1, s4);  // TV^T (chunk-blocked)

  {  // C^T_j[r,c] = sum_n' E0^T_j[r,n']*TV^T_j[c,n'] -> s0[j]
    GA g{};
    g.A = s3; g.lda = 1024; g.B = s4; g.ldb = 1024; g.K = 1024;
    g.Cb = s0; g.ldc = 1024;
    gemm_nt<M_CT><<<dim3(4, 4, 16), 512, 0, stream>>>(g);
  }
  prefix_s<<<1024, 256, 0, stream>>>(s0, s0, Wb0);  // S' = W0 - lam*prefix

  {  // Kp_i = -lam * mask16 ∘ (P_i @ TV_iᵀ) -> s4 (TV^T dead)
    GA g{};
    g.A = s2; g.lda = 1024; g.B = s1; g.ldb = 1024; g.K = 1024;
    g.Cb = s4; g.ldc = 1024;
    gemm_nt<M_KP><<<dim3(4, 4, 16), 512, 0, stream>>>(g);
  }
  {  // x1_i = Kp_i@E0_i (tri-K) + P_i@S'_i + x -> d_out ; H2 -> s1
    GA g{};
    g.A = s4; g.lda = 1024;        // Kp chunk
    g.B = s3; g.ldb = 1024;        // E0^T chunk-blocked
    g.A2 = s2; g.lda2 = 1024;      // P chunk
    g.B2 = s0; g.ldb2 = 1024;      // S' chunk
    g.xin = x; g.outf = out;
    g.alpha2 = a2; g.H2b = s1;     // fused tanh(alpha2*x1) (TV dead)
    gemm_nt<M_OUT><<<dim3(4, 4, 16), 512, 0, stream>>>(g);
  }
  {  // out = gelu(H2@Wp1ᵀ) * (H2@Wp2ᵀ) + x1  (one dispatch; V via LDS only)
    GA g{};
    g.A = s1; g.lda = 1024;
    g.B = W1b; g.ldb = 1024; g.Bb = W2b;
    g.K = 1024; g.outf = out;
    gemm_nt<M_UV><<<dim3(8, 64), 512, 0, stream>>>(g);
  }
}